// Round 1
// baseline (2615.604 us; speedup 1.0000x reference)
//
#include <hip/hip_runtime.h>
#include <hip/hip_bf16.h>

__device__ __forceinline__ float eluf(float x) {
    return x > 0.f ? x : expm1f(x);
}

// C[M,N] = act( A'[M,K] @ B[N,K]^T + bias ), A' = ELU_A ? elu(A) : A
// ACT: 0 = none, 1 = relu
template<bool ELU_A, int ACT, bool BIAS>
__global__ __launch_bounds__(128) void gemm_bt(
    const float* __restrict__ A, const float* __restrict__ B,
    const float* __restrict__ bias, float* __restrict__ C,
    int M, int N, int K)
{
    constexpr int BM = 64, BN = 64, BK = 16, TM = 4, TN = 8;
    __shared__ float As[BK][BM + 4];
    __shared__ float Bs[BK][BN + 4];
    const int t  = threadIdx.x;
    const int tx = t % 8;   // n-group (8 groups x 8 cols)
    const int ty = t / 8;   // m-group (16 groups x 4 rows)
    const int m0 = blockIdx.x * BM;
    const int n0 = blockIdx.y * BN;

    float acc[TM][TN] = {};

    for (int k0 = 0; k0 < K; k0 += BK) {
        // stage A tile (BM x BK), transposed into LDS
        #pragma unroll
        for (int idx = t; idx < BM * BK / 4; idx += 128) {
            int r  = idx / (BK / 4);
            int c4 = idx % (BK / 4);
            int row = m0 + r;
            float4 v = make_float4(0.f, 0.f, 0.f, 0.f);
            if (row < M) v = *(const float4*)&A[(size_t)row * K + k0 + c4 * 4];
            if (ELU_A) { v.x = eluf(v.x); v.y = eluf(v.y); v.z = eluf(v.z); v.w = eluf(v.w); }
            As[c4 * 4 + 0][r] = v.x; As[c4 * 4 + 1][r] = v.y;
            As[c4 * 4 + 2][r] = v.z; As[c4 * 4 + 3][r] = v.w;
        }
        // stage B tile (BN x BK), B is [N,K] row-major, transposed into LDS
        #pragma unroll
        for (int idx = t; idx < BN * BK / 4; idx += 128) {
            int n  = idx / (BK / 4);
            int c4 = idx % (BK / 4);
            float4 v = *(const float4*)&B[(size_t)(n0 + n) * K + k0 + c4 * 4];
            Bs[c4 * 4 + 0][n] = v.x; Bs[c4 * 4 + 1][n] = v.y;
            Bs[c4 * 4 + 2][n] = v.z; Bs[c4 * 4 + 3][n] = v.w;
        }
        __syncthreads();
        #pragma unroll
        for (int k = 0; k < BK; ++k) {
            float a[TM], b[TN];
            *(float4*)&a[0] = *(const float4*)&As[k][ty * TM];
            *(float4*)&b[0] = *(const float4*)&Bs[k][tx * TN];
            *(float4*)&b[4] = *(const float4*)&Bs[k][tx * TN + 4];
            #pragma unroll
            for (int i = 0; i < TM; ++i)
                #pragma unroll
                for (int j = 0; j < TN; ++j)
                    acc[i][j] = fmaf(a[i], b[j], acc[i][j]);
        }
        __syncthreads();
    }

    #pragma unroll
    for (int i = 0; i < TM; ++i) {
        int row = m0 + ty * TM + i;
        if (row >= M) continue;
        #pragma unroll
        for (int j4 = 0; j4 < TN / 4; ++j4) {
            float4 v;
            float* vp = (float*)&v;
            #pragma unroll
            for (int j = 0; j < 4; ++j) {
                float xv = acc[i][j4 * 4 + j];
                if (BIAS) xv += bias[n0 + tx * TN + j4 * 4 + j];
                if (ACT == 1) xv = fmaxf(xv, 0.f);
                vp[j] = xv;
            }
            *(float4*)&C[(size_t)row * N + n0 + tx * TN + j4 * 4] = v;
        }
    }
}

// h[row[e]] += z[col[e]]  (D = D4*4 floats per node)
template<int D4>
__global__ __launch_bounds__(256) void scatter_add_k(
    const int* __restrict__ row, const int* __restrict__ col,
    const float* __restrict__ z, float* __restrict__ h, int E)
{
    const int total = E * D4;
    for (int i = blockIdx.x * 256 + threadIdx.x; i < total; i += gridDim.x * 256) {
        int e = i / D4;
        int c = i % D4;
        int r = row[e], cl = col[e];
        float4 v = *(const float4*)&z[(size_t)cl * (D4 * 4) + c * 4];
        float* dst = &h[(size_t)r * (D4 * 4) + c * 4];
        atomicAdd(dst + 0, v.x);
        atomicAdd(dst + 1, v.y);
        atomicAdd(dst + 2, v.z);
        atomicAdd(dst + 3, v.w);
    }
}

__global__ __launch_bounds__(256) void pool_kernel(
    const float* __restrict__ h2, const int* __restrict__ batch,
    float* __restrict__ gsum, float* __restrict__ cnt, int Nn)
{
    int total = Nn * 16;
    for (int i = blockIdx.x * 256 + threadIdx.x; i < total; i += gridDim.x * 256) {
        int n = i / 16, c = i % 16;
        int b = batch[n];
        float4 v = *(const float4*)&h2[(size_t)n * 64 + c * 4];
        float* dst = &gsum[(size_t)b * 64 + c * 4];
        atomicAdd(dst + 0, v.x);
        atomicAdd(dst + 1, v.y);
        atomicAdd(dst + 2, v.z);
        atomicAdd(dst + 3, v.w);
        if (c == 0) atomicAdd(&cnt[b], 1.0f);
    }
}

__global__ __launch_bounds__(256) void divide_kernel(
    const float* __restrict__ gsum, const float* __restrict__ cnt,
    float* __restrict__ g)
{
    int i = blockIdx.x * 256 + threadIdx.x;   // exactly 512*64
    g[i] = gsum[i] / fmaxf(cnt[i >> 6], 1.0f);
}

// out[512,4] = softmax( A[512,1024] @ W[4,1024]^T + bias )
__global__ __launch_bounds__(256) void final_kernel(
    const float* __restrict__ A, const float* __restrict__ W,
    const float* __restrict__ bias, float* __restrict__ out)
{
    int i = blockIdx.x * 256 + threadIdx.x;   // exactly 512*4
    int r = i >> 2, o = i & 3;
    float s = bias[o];
    const float4* a = (const float4*)&A[(size_t)r * 1024];
    const float4* w = (const float4*)&W[(size_t)o * 1024];
    #pragma unroll 4
    for (int k = 0; k < 256; ++k) {
        float4 av = a[k], wv = w[k];
        s += av.x * wv.x + av.y * wv.y + av.z * wv.z + av.w * wv.w;
    }
    // softmax across the 4 lanes of this row (lanes are contiguous: r*4+o)
    float m = s;
    m = fmaxf(m, __shfl_xor(m, 1));
    m = fmaxf(m, __shfl_xor(m, 2));
    float e = __expf(s - m);
    float sum = e;
    sum += __shfl_xor(sum, 1);
    sum += __shfl_xor(sum, 2);
    out[i] = e / sum;
}

extern "C" void kernel_launch(void* const* d_in, const int* in_sizes, int n_in,
                              void* d_out, int out_size, void* d_ws, size_t ws_size,
                              hipStream_t stream)
{
    const float* x     = (const float*)d_in[0];
    const int*   ei    = (const int*)d_in[1];
    const int*   batch = (const int*)d_in[2];
    const float* fc1_w = (const float*)d_in[3];   // [4,32,128] -> [128,128]
    const float* fc2_w = (const float*)d_in[5];   // [1,64,128] -> [64,128]
    const float* w1 = (const float*)d_in[7];  const float* b1 = (const float*)d_in[8];
    const float* w2 = (const float*)d_in[9];  const float* b2 = (const float*)d_in[10];
    const float* w3 = (const float*)d_in[11]; const float* b3 = (const float*)d_in[12];
    const float* w4 = (const float*)d_in[13]; const float* b4 = (const float*)d_in[14];
    const float* w5 = (const float*)d_in[15]; const float* b5 = (const float*)d_in[16];
    float* out = (float*)d_out;

    const int N = 50000, E = 800000;
    const int* rowp = ei;        // edge_index[0]
    const int* colp = ei + E;    // edge_index[1]

    float* ws   = (float*)d_ws;
    float* bufA = ws;                 // 6,400,000 floats (z1, later z2)
    float* bufB = ws + 6400000;       // 6,400,000 floats (h1, later h2)
    float* gsum = ws + 12800000;      // 32768
    float* cnt  = gsum + 32768;       // 512
    float* g    = cnt + 512;          // 32768
    float* a1   = g + 32768;          // 524288
    float* a2   = a1 + 524288;        // 524288

    // 1. z1 = x @ W1^T   [50000,128]
    gemm_bt<false, 0, false><<<dim3(782, 2), 128, 0, stream>>>(x, fc1_w, nullptr, bufA, N, 128, 128);

    // 2. h1[row] += z1[col]
    hipMemsetAsync(bufB, 0, (size_t)6400000 * sizeof(float), stream);
    scatter_add_k<32><<<4096, 256, 0, stream>>>(rowp, colp, bufA, bufB, E);

    // 3. z2 = elu(h1) @ W2^T   [50000,64]
    gemm_bt<true, 0, false><<<dim3(782, 1), 128, 0, stream>>>(bufB, fc2_w, nullptr, bufA, N, 64, 128);

    // 4. h2[row] += z2[col]
    hipMemsetAsync(bufB, 0, (size_t)3200000 * sizeof(float), stream);
    scatter_add_k<16><<<4096, 256, 0, stream>>>(rowp, colp, bufA, bufB, E);

    // 5. mean-pool by graph
    hipMemsetAsync(gsum, 0, (size_t)(32768 + 512) * sizeof(float), stream);
    pool_kernel<<<3125, 256, 0, stream>>>(bufB, batch, gsum, cnt, N);
    divide_kernel<<<128, 256, 0, stream>>>(gsum, cnt, g);

    // 6. MLP
    gemm_bt<false, 1, true><<<dim3(8, 16), 128, 0, stream>>>(g,  w1, b1, a1, 512, 1024, 64);
    gemm_bt<false, 1, true><<<dim3(8, 16), 128, 0, stream>>>(a1, w2, b2, a2, 512, 1024, 1024);
    gemm_bt<false, 1, true><<<dim3(8, 16), 128, 0, stream>>>(a2, w3, b3, a1, 512, 1024, 1024);
    gemm_bt<false, 1, true><<<dim3(8, 16), 128, 0, stream>>>(a1, w4, b4, a2, 512, 1024, 1024);

    // 7. final layer + softmax
    final_kernel<<<8, 256, 0, stream>>>(a2, w5, b5, out);
}

// Round 2
// 771.307 us; speedup vs baseline: 3.3911x; 3.3911x over previous
//
#include <hip/hip_runtime.h>
#include <hip/hip_bf16.h>

__device__ __forceinline__ float eluf(float x) {
    return x > 0.f ? x : expm1f(x);
}

// C[M,N] = act( A'[M,K] @ B[N,K]^T + bias ), A' = ELU_A ? elu(A) : A
// ACT: 0 = none, 1 = relu
template<bool ELU_A, int ACT, bool BIAS>
__global__ __launch_bounds__(128) void gemm_bt(
    const float* __restrict__ A, const float* __restrict__ B,
    const float* __restrict__ bias, float* __restrict__ C,
    int M, int N, int K)
{
    constexpr int BM = 64, BN = 64, BK = 16, TM = 4, TN = 8;
    __shared__ float As[BK][BM + 4];
    __shared__ float Bs[BK][BN + 4];
    const int t  = threadIdx.x;
    const int tx = t % 8;   // n-group (8 groups x 8 cols)
    const int ty = t / 8;   // m-group (16 groups x 4 rows)
    const int m0 = blockIdx.x * BM;
    const int n0 = blockIdx.y * BN;

    float acc[TM][TN] = {};

    for (int k0 = 0; k0 < K; k0 += BK) {
        #pragma unroll
        for (int idx = t; idx < BM * BK / 4; idx += 128) {
            int r  = idx / (BK / 4);
            int c4 = idx % (BK / 4);
            int row = m0 + r;
            float4 v = make_float4(0.f, 0.f, 0.f, 0.f);
            if (row < M) v = *(const float4*)&A[(size_t)row * K + k0 + c4 * 4];
            if (ELU_A) { v.x = eluf(v.x); v.y = eluf(v.y); v.z = eluf(v.z); v.w = eluf(v.w); }
            As[c4 * 4 + 0][r] = v.x; As[c4 * 4 + 1][r] = v.y;
            As[c4 * 4 + 2][r] = v.z; As[c4 * 4 + 3][r] = v.w;
        }
        #pragma unroll
        for (int idx = t; idx < BN * BK / 4; idx += 128) {
            int n  = idx / (BK / 4);
            int c4 = idx % (BK / 4);
            float4 v = *(const float4*)&B[(size_t)(n0 + n) * K + k0 + c4 * 4];
            Bs[c4 * 4 + 0][n] = v.x; Bs[c4 * 4 + 1][n] = v.y;
            Bs[c4 * 4 + 2][n] = v.z; Bs[c4 * 4 + 3][n] = v.w;
        }
        __syncthreads();
        #pragma unroll
        for (int k = 0; k < BK; ++k) {
            float a[TM], b[TN];
            *(float4*)&a[0] = *(const float4*)&As[k][ty * TM];
            *(float4*)&b[0] = *(const float4*)&Bs[k][tx * TN];
            *(float4*)&b[4] = *(const float4*)&Bs[k][tx * TN + 4];
            #pragma unroll
            for (int i = 0; i < TM; ++i)
                #pragma unroll
                for (int j = 0; j < TN; ++j)
                    acc[i][j] = fmaf(a[i], b[j], acc[i][j]);
        }
        __syncthreads();
    }

    #pragma unroll
    for (int i = 0; i < TM; ++i) {
        int row = m0 + ty * TM + i;
        if (row >= M) continue;
        #pragma unroll
        for (int j4 = 0; j4 < TN / 4; ++j4) {
            float4 v;
            float* vp = (float*)&v;
            #pragma unroll
            for (int j = 0; j < 4; ++j) {
                float xv = acc[i][j4 * 4 + j];
                if (BIAS) xv += bias[n0 + tx * TN + j4 * 4 + j];
                if (ACT == 1) xv = fmaxf(xv, 0.f);
                vp[j] = xv;
            }
            *(float4*)&C[(size_t)row * N + n0 + tx * TN + j4 * 4] = v;
        }
    }
}

// ---------- CSR build ----------
__global__ __launch_bounds__(256) void hist_kernel(
    const int* __restrict__ row, int* __restrict__ deg, int E)
{
    for (int e = blockIdx.x * 256 + threadIdx.x; e < E; e += gridDim.x * 256)
        atomicAdd(&deg[row[e]], 1);
}

__global__ __launch_bounds__(256) void scan1_kernel(
    const int* __restrict__ deg, int* __restrict__ part,
    int* __restrict__ blocksum, int n)
{
    __shared__ int s[256];
    int i = blockIdx.x * 256 + threadIdx.x;
    int v = (i < n) ? deg[i] : 0;
    s[threadIdx.x] = v;
    __syncthreads();
    #pragma unroll
    for (int off = 1; off < 256; off <<= 1) {
        int t = (threadIdx.x >= off) ? s[threadIdx.x - off] : 0;
        __syncthreads();
        if (threadIdx.x >= off) s[threadIdx.x] += t;
        __syncthreads();
    }
    if (i < n) part[i] = s[threadIdx.x] - v;   // exclusive
    if (threadIdx.x == 255) blocksum[blockIdx.x] = s[255];
}

__global__ __launch_bounds__(256) void scan2_kernel(
    const int* __restrict__ blocksum, int* __restrict__ blockoff, int nb)
{
    __shared__ int s[256];
    int v = (threadIdx.x < nb) ? blocksum[threadIdx.x] : 0;
    s[threadIdx.x] = v;
    __syncthreads();
    #pragma unroll
    for (int off = 1; off < 256; off <<= 1) {
        int t = (threadIdx.x >= off) ? s[threadIdx.x - off] : 0;
        __syncthreads();
        if (threadIdx.x >= off) s[threadIdx.x] += t;
        __syncthreads();
    }
    blockoff[threadIdx.x] = s[threadIdx.x] - v;   // exclusive
}

__global__ __launch_bounds__(256) void scan3_kernel(
    const int* __restrict__ part, const int* __restrict__ blockoff,
    int* __restrict__ rowptr, int* __restrict__ cursor, int n, int E)
{
    int i = blockIdx.x * 256 + threadIdx.x;
    if (i < n) {
        int v = part[i] + blockoff[i >> 8];
        rowptr[i] = v;
        cursor[i] = v;
    }
    if (i == 0) rowptr[n] = E;
}

__global__ __launch_bounds__(256) void scatter_cols_kernel(
    const int* __restrict__ row, const int* __restrict__ col,
    int* __restrict__ cursor, int* __restrict__ ecol, int E)
{
    for (int e = blockIdx.x * 256 + threadIdx.x; e < E; e += gridDim.x * 256) {
        int p = atomicAdd(&cursor[row[e]], 1);
        ecol[p] = col[e];
    }
}

// ---------- gather-sum:  h[n] = sum_{e in csr row n} z[ecol[e]]  ----------
// DQ lanes per node, each lane owns one float4 (D = DQ*4)
template<int DQ>
__global__ __launch_bounds__(256) void gather_sum(
    const int* __restrict__ rowptr, const int* __restrict__ ecol,
    const float* __restrict__ z, float* __restrict__ h, int N)
{
    constexpr int GPB = 256 / DQ;
    const int node = blockIdx.x * GPB + threadIdx.x / DQ;
    const int lane = threadIdx.x % DQ;
    if (node >= N) return;
    const int start = rowptr[node], end = rowptr[node + 1];
    float ax = 0.f, ay = 0.f, az = 0.f, aw = 0.f;
    for (int base = start; base < end; base += DQ) {
        int myidx = base + lane;
        int c = (myidx < end) ? ecol[myidx] : 0;
        int cnt = min(DQ, end - base);
        for (int j = 0; j < cnt; ++j) {
            int cj = __shfl(c, j, DQ);
            float4 zv = *(const float4*)&z[(size_t)cj * (DQ * 4) + lane * 4];
            ax += zv.x; ay += zv.y; az += zv.z; aw += zv.w;
        }
    }
    *(float4*)&h[(size_t)node * (DQ * 4) + lane * 4] = make_float4(ax, ay, az, aw);
}

__global__ __launch_bounds__(256) void pool_kernel(
    const float* __restrict__ h2, const int* __restrict__ batch,
    float* __restrict__ gsum, float* __restrict__ cnt, int Nn)
{
    int total = Nn * 16;
    for (int i = blockIdx.x * 256 + threadIdx.x; i < total; i += gridDim.x * 256) {
        int n = i / 16, c = i % 16;
        int b = batch[n];
        float4 v = *(const float4*)&h2[(size_t)n * 64 + c * 4];
        float* dst = &gsum[(size_t)b * 64 + c * 4];
        atomicAdd(dst + 0, v.x);
        atomicAdd(dst + 1, v.y);
        atomicAdd(dst + 2, v.z);
        atomicAdd(dst + 3, v.w);
        if (c == 0) atomicAdd(&cnt[b], 1.0f);
    }
}

__global__ __launch_bounds__(256) void divide_kernel(
    const float* __restrict__ gsum, const float* __restrict__ cnt,
    float* __restrict__ g)
{
    int i = blockIdx.x * 256 + threadIdx.x;   // exactly 512*64
    g[i] = gsum[i] / fmaxf(cnt[i >> 6], 1.0f);
}

// out[512,4] = softmax( A[512,1024] @ W[4,1024]^T + bias )
__global__ __launch_bounds__(256) void final_kernel(
    const float* __restrict__ A, const float* __restrict__ W,
    const float* __restrict__ bias, float* __restrict__ out)
{
    int i = blockIdx.x * 256 + threadIdx.x;   // exactly 512*4
    int r = i >> 2, o = i & 3;
    float s = bias[o];
    const float4* a = (const float4*)&A[(size_t)r * 1024];
    const float4* w = (const float4*)&W[(size_t)o * 1024];
    #pragma unroll 4
    for (int k = 0; k < 256; ++k) {
        float4 av = a[k], wv = w[k];
        s += av.x * wv.x + av.y * wv.y + av.z * wv.z + av.w * wv.w;
    }
    float m = s;
    m = fmaxf(m, __shfl_xor(m, 1));
    m = fmaxf(m, __shfl_xor(m, 2));
    float e = __expf(s - m);
    float sum = e;
    sum += __shfl_xor(sum, 1);
    sum += __shfl_xor(sum, 2);
    out[i] = e / sum;
}

extern "C" void kernel_launch(void* const* d_in, const int* in_sizes, int n_in,
                              void* d_out, int out_size, void* d_ws, size_t ws_size,
                              hipStream_t stream)
{
    const float* x     = (const float*)d_in[0];
    const int*   ei    = (const int*)d_in[1];
    const int*   batch = (const int*)d_in[2];
    const float* fc1_w = (const float*)d_in[3];   // [4,32,128] -> [128,128]
    const float* fc2_w = (const float*)d_in[5];   // [1,64,128] -> [64,128]
    const float* w1 = (const float*)d_in[7];  const float* b1 = (const float*)d_in[8];
    const float* w2 = (const float*)d_in[9];  const float* b2 = (const float*)d_in[10];
    const float* w3 = (const float*)d_in[11]; const float* b3 = (const float*)d_in[12];
    const float* w4 = (const float*)d_in[13]; const float* b4 = (const float*)d_in[14];
    const float* w5 = (const float*)d_in[15]; const float* b5 = (const float*)d_in[16];
    float* out = (float*)d_out;

    const int N = 50000, E = 800000;
    const int* rowp = ei;        // edge_index[0]  (destinations)
    const int* colp = ei + E;    // edge_index[1]  (sources)

    // ---- workspace layout (floats) ----
    float* ws   = (float*)d_ws;
    float* bufA = ws;                         // 6,400,000  (z1, then z2)
    float* bufB = ws + 6400000;               // 6,400,000  (h1, then h2)
    float* gsum = ws + 12800000;              // 32768
    float* cnt  = gsum + 32768;               // 512
    float* g    = cnt + 512;                  // 32768
    // persistent CSR arrays
    int* rowptr = (int*)(g + 32768);          // 50001 (pad to 50004)
    int* ecol   = rowptr + 50004;             // 800000
    // MLP activations alias bufA (free after gather2 reads z2)
    float* a1 = bufA;                         // 524288
    float* a2 = bufA + 524288;                // 524288
    // CSR-build temporaries alias bufA/bufB (free before GEMM1)
    int* deg      = (int*)bufA;               // 50000
    int* part     = (int*)bufA + 65536;       // 50000
    int* blocksum = (int*)bufA + 131072;      // 256
    int* blockoff = (int*)bufA + 131328;      // 256
    int* cursor   = (int*)bufB;               // 50000

    const int NB = (N + 255) / 256;           // 196 scan blocks

    // ---- build CSR (group edges by destination row) ----
    hipMemsetAsync(deg, 0, (size_t)N * sizeof(int), stream);
    hist_kernel<<<1024, 256, 0, stream>>>(rowp, deg, E);
    scan1_kernel<<<NB, 256, 0, stream>>>(deg, part, blocksum, N);
    scan2_kernel<<<1, 256, 0, stream>>>(blocksum, blockoff, NB);
    scan3_kernel<<<NB, 256, 0, stream>>>(part, blockoff, rowptr, cursor, N, E);
    scatter_cols_kernel<<<1024, 256, 0, stream>>>(rowp, colp, cursor, ecol, E);

    // ---- layer 1: z1 = x @ W1^T ; h1 = gather-sum(z1) ----
    gemm_bt<false, 0, false><<<dim3(782, 2), 128, 0, stream>>>(x, fc1_w, nullptr, bufA, N, 128, 128);
    gather_sum<32><<<(N + 7) / 8, 256, 0, stream>>>(rowptr, ecol, bufA, bufB, N);

    // ---- layer 2: z2 = elu(h1) @ W2^T ; h2 = gather-sum(z2) ----
    gemm_bt<true, 0, false><<<dim3(782, 1), 128, 0, stream>>>(bufB, fc2_w, nullptr, bufA, N, 64, 128);
    gather_sum<16><<<(N + 15) / 16, 256, 0, stream>>>(rowptr, ecol, bufA, bufB, N);

    // ---- mean-pool by graph ----
    hipMemsetAsync(gsum, 0, (size_t)(32768 + 512) * sizeof(float), stream);
    pool_kernel<<<3125, 256, 0, stream>>>(bufB, batch, gsum, cnt, N);
    divide_kernel<<<128, 256, 0, stream>>>(gsum, cnt, g);

    // ---- MLP (a1/a2 alias bufA, safe: z2 consumed) ----
    gemm_bt<false, 1, true><<<dim3(8, 16), 128, 0, stream>>>(g,  w1, b1, a1, 512, 1024, 64);
    gemm_bt<false, 1, true><<<dim3(8, 16), 128, 0, stream>>>(a1, w2, b2, a2, 512, 1024, 1024);
    gemm_bt<false, 1, true><<<dim3(8, 16), 128, 0, stream>>>(a2, w3, b3, a1, 512, 1024, 1024);
    gemm_bt<false, 1, true><<<dim3(8, 16), 128, 0, stream>>>(a1, w4, b4, a2, 512, 1024, 1024);

    // ---- final layer + softmax ----
    final_kernel<<<8, 256, 0, stream>>>(a2, w5, b5, out);
}

// Round 3
// 454.827 us; speedup vs baseline: 5.7508x; 1.6958x over previous
//
#include <hip/hip_runtime.h>
#include <hip/hip_bf16.h>

__device__ __forceinline__ float eluf(float x) {
    return x > 0.f ? x : expm1f(x);
}

// C[M,N] = act( A'[M,K] @ B[N,K]^T + bias ), A' = ELU_A ? elu(A) : A
// ACT: 0 = none, 1 = relu.  SPLIT: write raw partial to C + blockIdx.z*M*N,
// covering K-chunk [blockIdx.z*kChunk, +kChunk)
template<bool ELU_A, int ACT, bool BIAS, bool SPLIT>
__global__ __launch_bounds__(256) void gemm256(
    const float* __restrict__ A, const float* __restrict__ B,
    const float* __restrict__ bias, float* __restrict__ C,
    int M, int N, int K, int kChunk)
{
    constexpr int BM = 64, BN = 64, BK = 16;
    __shared__ float As[BK][BM + 4];
    __shared__ float Bs[BK][BN + 4];
    const int t  = threadIdx.x;
    const int tx = t & 15;    // n-group (16 x 4 cols)
    const int ty = t >> 4;    // m-group (16 x 4 rows)
    const int m0 = blockIdx.x * BM;
    const int n0 = blockIdx.y * BN;
    const int kBeg = SPLIT ? blockIdx.z * kChunk : 0;
    const int kEnd = SPLIT ? kBeg + kChunk : K;

    const int sr = t >> 2;    // staging row 0..63
    const int sc = t & 3;     // staging col4 0..3

    float acc[4][4] = {};

    for (int k0 = kBeg; k0 < kEnd; k0 += BK) {
        // A tile: 64 x 16, one float4 per thread
        {
            int row = m0 + sr;
            float4 v = make_float4(0.f, 0.f, 0.f, 0.f);
            if (row < M) v = *(const float4*)&A[(size_t)row * K + k0 + sc * 4];
            if (ELU_A) { v.x = eluf(v.x); v.y = eluf(v.y); v.z = eluf(v.z); v.w = eluf(v.w); }
            As[sc * 4 + 0][sr] = v.x; As[sc * 4 + 1][sr] = v.y;
            As[sc * 4 + 2][sr] = v.z; As[sc * 4 + 3][sr] = v.w;
        }
        // B tile: 64 x 16
        {
            float4 v = *(const float4*)&B[(size_t)(n0 + sr) * K + k0 + sc * 4];
            Bs[sc * 4 + 0][sr] = v.x; Bs[sc * 4 + 1][sr] = v.y;
            Bs[sc * 4 + 2][sr] = v.z; Bs[sc * 4 + 3][sr] = v.w;
        }
        __syncthreads();
        #pragma unroll
        for (int k = 0; k < BK; ++k) {
            float a[4], b[4];
            *(float4*)&a[0] = *(const float4*)&As[k][ty * 4];
            *(float4*)&b[0] = *(const float4*)&Bs[k][tx * 4];
            #pragma unroll
            for (int i = 0; i < 4; ++i)
                #pragma unroll
                for (int j = 0; j < 4; ++j)
                    acc[i][j] = fmaf(a[i], b[j], acc[i][j]);
        }
        __syncthreads();
    }

    float* Cw = SPLIT ? C + (size_t)blockIdx.z * M * N : C;
    #pragma unroll
    for (int i = 0; i < 4; ++i) {
        int row = m0 + ty * 4 + i;
        if (row >= M) continue;
        float4 v;
        float* vp = (float*)&v;
        #pragma unroll
        for (int j = 0; j < 4; ++j) {
            float xv = acc[i][j];
            if (!SPLIT) {
                if (BIAS) xv += bias[n0 + tx * 4 + j];
                if (ACT == 1) xv = fmaxf(xv, 0.f);
            }
            vp[j] = xv;
        }
        *(float4*)&Cw[(size_t)row * N + n0 + tx * 4] = v;
    }
}

// C[i] = relu( sum_z part[z][i] + bias[i % N] ), float4-wide, N % 4 == 0
__global__ __launch_bounds__(256) void reduce_bias_relu(
    const float* __restrict__ part, const float* __restrict__ bias,
    float* __restrict__ C, int MN4, int N, int KS)
{
    int i = blockIdx.x * 256 + threadIdx.x;
    if (i >= MN4) return;
    float4 s = *(const float4*)&part[(size_t)i * 4];
    for (int z = 1; z < KS; ++z) {
        float4 p = *(const float4*)&part[(size_t)z * MN4 * 4 + (size_t)i * 4];
        s.x += p.x; s.y += p.y; s.z += p.z; s.w += p.w;
    }
    float4 bv = *(const float4*)&bias[(i * 4) & (N - 1)];
    s.x = fmaxf(s.x + bv.x, 0.f);
    s.y = fmaxf(s.y + bv.y, 0.f);
    s.z = fmaxf(s.z + bv.z, 0.f);
    s.w = fmaxf(s.w + bv.w, 0.f);
    *(float4*)&C[(size_t)i * 4] = s;
}

// ---------- CSR build ----------
__global__ __launch_bounds__(256) void hist_kernel(
    const int* __restrict__ row, int* __restrict__ deg, int E)
{
    for (int e = blockIdx.x * 256 + threadIdx.x; e < E; e += gridDim.x * 256)
        atomicAdd(&deg[row[e]], 1);
}

__global__ __launch_bounds__(256) void scan1_kernel(
    const int* __restrict__ deg, int* __restrict__ part,
    int* __restrict__ blocksum, int n)
{
    __shared__ int s[256];
    int i = blockIdx.x * 256 + threadIdx.x;
    int v = (i < n) ? deg[i] : 0;
    s[threadIdx.x] = v;
    __syncthreads();
    #pragma unroll
    for (int off = 1; off < 256; off <<= 1) {
        int t = (threadIdx.x >= off) ? s[threadIdx.x - off] : 0;
        __syncthreads();
        if (threadIdx.x >= off) s[threadIdx.x] += t;
        __syncthreads();
    }
    if (i < n) part[i] = s[threadIdx.x] - v;   // exclusive
    if (threadIdx.x == 255) blocksum[blockIdx.x] = s[255];
}

__global__ __launch_bounds__(256) void scan2_kernel(
    const int* __restrict__ blocksum, int* __restrict__ blockoff, int nb)
{
    __shared__ int s[256];
    int v = (threadIdx.x < nb) ? blocksum[threadIdx.x] : 0;
    s[threadIdx.x] = v;
    __syncthreads();
    #pragma unroll
    for (int off = 1; off < 256; off <<= 1) {
        int t = (threadIdx.x >= off) ? s[threadIdx.x - off] : 0;
        __syncthreads();
        if (threadIdx.x >= off) s[threadIdx.x] += t;
        __syncthreads();
    }
    blockoff[threadIdx.x] = s[threadIdx.x] - v;   // exclusive
}

__global__ __launch_bounds__(256) void scan3_kernel(
    const int* __restrict__ part, const int* __restrict__ blockoff,
    int* __restrict__ rowptr, int* __restrict__ cursor, int n, int E)
{
    int i = blockIdx.x * 256 + threadIdx.x;
    if (i < n) {
        int v = part[i] + blockoff[i >> 8];
        rowptr[i] = v;
        cursor[i] = v;
    }
    if (i == 0) rowptr[n] = E;
}

__global__ __launch_bounds__(256) void scatter_cols_kernel(
    const int* __restrict__ row, const int* __restrict__ col,
    int* __restrict__ cursor, int* __restrict__ ecol, int E)
{
    for (int e = blockIdx.x * 256 + threadIdx.x; e < E; e += gridDim.x * 256) {
        int p = atomicAdd(&cursor[row[e]], 1);
        ecol[p] = col[e];
    }
}

// ---------- gather-sum:  h[n] = sum_{e in csr row n} z[ecol[e]]  ----------
template<int DQ>
__global__ __launch_bounds__(256) void gather_sum(
    const int* __restrict__ rowptr, const int* __restrict__ ecol,
    const float* __restrict__ z, float* __restrict__ h, int N)
{
    constexpr int GPB = 256 / DQ;
    const int node = blockIdx.x * GPB + threadIdx.x / DQ;
    const int lane = threadIdx.x % DQ;
    if (node >= N) return;
    const int start = rowptr[node], end = rowptr[node + 1];
    float ax = 0.f, ay = 0.f, az = 0.f, aw = 0.f;
    for (int base = start; base < end; base += DQ) {
        int myidx = base + lane;
        int c = (myidx < end) ? ecol[myidx] : 0;
        int cnt = min(DQ, end - base);
        for (int j = 0; j < cnt; ++j) {
            int cj = __shfl(c, j, DQ);
            float4 zv = *(const float4*)&z[(size_t)cj * (DQ * 4) + lane * 4];
            ax += zv.x; ay += zv.y; az += zv.z; aw += zv.w;
        }
    }
    *(float4*)&h[(size_t)node * (DQ * 4) + lane * 4] = make_float4(ax, ay, az, aw);
}

__global__ __launch_bounds__(256) void pool_kernel(
    const float* __restrict__ h2, const int* __restrict__ batch,
    float* __restrict__ gsum, float* __restrict__ cnt, int Nn)
{
    int total = Nn * 16;
    for (int i = blockIdx.x * 256 + threadIdx.x; i < total; i += gridDim.x * 256) {
        int n = i / 16, c = i % 16;
        int b = batch[n];
        float4 v = *(const float4*)&h2[(size_t)n * 64 + c * 4];
        float* dst = &gsum[(size_t)b * 64 + c * 4];
        atomicAdd(dst + 0, v.x);
        atomicAdd(dst + 1, v.y);
        atomicAdd(dst + 2, v.z);
        atomicAdd(dst + 3, v.w);
        if (c == 0) atomicAdd(&cnt[b], 1.0f);
    }
}

__global__ __launch_bounds__(256) void divide_kernel(
    const float* __restrict__ gsum, const float* __restrict__ cnt,
    float* __restrict__ g)
{
    int i = blockIdx.x * 256 + threadIdx.x;   // exactly 512*64
    g[i] = gsum[i] / fmaxf(cnt[i >> 6], 1.0f);
}

// out[512,4] = softmax( A[512,1024] @ W[4,1024]^T + bias )
__global__ __launch_bounds__(256) void final_kernel(
    const float* __restrict__ A, const float* __restrict__ W,
    const float* __restrict__ bias, float* __restrict__ out)
{
    int i = blockIdx.x * 256 + threadIdx.x;   // exactly 512*4
    int r = i >> 2, o = i & 3;
    float s = bias[o];
    const float4* a = (const float4*)&A[(size_t)r * 1024];
    const float4* w = (const float4*)&W[(size_t)o * 1024];
    #pragma unroll 4
    for (int k = 0; k < 256; ++k) {
        float4 av = a[k], wv = w[k];
        s += av.x * wv.x + av.y * wv.y + av.z * wv.z + av.w * wv.w;
    }
    float m = s;
    m = fmaxf(m, __shfl_xor(m, 1));
    m = fmaxf(m, __shfl_xor(m, 2));
    float e = __expf(s - m);
    float sum = e;
    sum += __shfl_xor(sum, 1);
    sum += __shfl_xor(sum, 2);
    out[i] = e / sum;
}

extern "C" void kernel_launch(void* const* d_in, const int* in_sizes, int n_in,
                              void* d_out, int out_size, void* d_ws, size_t ws_size,
                              hipStream_t stream)
{
    const float* x     = (const float*)d_in[0];
    const int*   ei    = (const int*)d_in[1];
    const int*   batch = (const int*)d_in[2];
    const float* fc1_w = (const float*)d_in[3];   // [4,32,128] -> [128,128]
    const float* fc2_w = (const float*)d_in[5];   // [1,64,128] -> [64,128]
    const float* w1 = (const float*)d_in[7];  const float* b1 = (const float*)d_in[8];
    const float* w2 = (const float*)d_in[9];  const float* b2 = (const float*)d_in[10];
    const float* w3 = (const float*)d_in[11]; const float* b3 = (const float*)d_in[12];
    const float* w4 = (const float*)d_in[13]; const float* b4 = (const float*)d_in[14];
    const float* w5 = (const float*)d_in[15]; const float* b5 = (const float*)d_in[16];
    float* out = (float*)d_out;

    const int N = 50000, E = 800000;
    const int* rowp = ei;        // edge_index[0]  (destinations)
    const int* colp = ei + E;    // edge_index[1]  (sources)

    // ---- workspace layout (floats) ----
    float* ws   = (float*)d_ws;
    float* bufA = ws;                         // 6,400,000  (z1, then z2)
    float* bufB = ws + 6400000;               // 6,400,000  (h1, then h2, then split-K partials)
    float* gsum = ws + 12800000;              // 32768
    float* cnt  = gsum + 32768;               // 512
    float* g    = cnt + 512;                  // 32768
    int* rowptr = (int*)(g + 32768);          // 50001 (pad to 50004)
    int* ecol   = rowptr + 50004;             // 800000
    // MLP activations alias bufA (free after gather2 reads z2)
    float* a1 = bufA;                         // 524288
    float* a2 = bufA + 524288;                // 524288
    float* cpart = bufB;                      // 8 * 524288 = 4,194,304 (bufB free after pool)
    // CSR-build temporaries alias bufA/bufB (free before GEMM1)
    int* deg      = (int*)bufA;               // 50000
    int* part     = (int*)bufA + 65536;       // 50000
    int* blocksum = (int*)bufA + 131072;      // 256
    int* blockoff = (int*)bufA + 131328;      // 256
    int* cursor   = (int*)bufB;               // 50000

    const int NB = (N + 255) / 256;           // 196 scan blocks

    // ---- build CSR (group edges by destination row) ----
    hipMemsetAsync(deg, 0, (size_t)N * sizeof(int), stream);
    hist_kernel<<<1024, 256, 0, stream>>>(rowp, deg, E);
    scan1_kernel<<<NB, 256, 0, stream>>>(deg, part, blocksum, N);
    scan2_kernel<<<1, 256, 0, stream>>>(blocksum, blockoff, NB);
    scan3_kernel<<<NB, 256, 0, stream>>>(part, blockoff, rowptr, cursor, N, E);
    scatter_cols_kernel<<<1024, 256, 0, stream>>>(rowp, colp, cursor, ecol, E);

    // ---- layer 1: z1 = x @ W1^T ; h1 = gather-sum(z1) ----
    gemm256<false, 0, false, false><<<dim3(782, 2, 1), 256, 0, stream>>>(x, fc1_w, nullptr, bufA, N, 128, 128, 0);
    gather_sum<32><<<(N + 7) / 8, 256, 0, stream>>>(rowptr, ecol, bufA, bufB, N);

    // ---- layer 2: z2 = elu(h1) @ W2^T ; h2 = gather-sum(z2) ----
    gemm256<true, 0, false, false><<<dim3(782, 1, 1), 256, 0, stream>>>(bufB, fc2_w, nullptr, bufA, N, 64, 128, 0);
    gather_sum<16><<<(N + 15) / 16, 256, 0, stream>>>(rowptr, ecol, bufA, bufB, N);

    // ---- mean-pool by graph ----
    hipMemsetAsync(gsum, 0, (size_t)(32768 + 512) * sizeof(float), stream);
    pool_kernel<<<3125, 256, 0, stream>>>(bufB, batch, gsum, cnt, N);
    divide_kernel<<<128, 256, 0, stream>>>(gsum, cnt, g);

    // ---- MLP ----
    // mlp1: K=64, direct
    gemm256<false, 1, true, false><<<dim3(8, 16, 1), 256, 0, stream>>>(g, w1, b1, a1, 512, 1024, 64, 0);
    // mlp2..4: K=1024, split-K=8 (chunk 128) + reduce(bias+relu)
    gemm256<false, 0, false, true><<<dim3(8, 16, 8), 256, 0, stream>>>(a1, w2, nullptr, cpart, 512, 1024, 1024, 128);
    reduce_bias_relu<<<512, 256, 0, stream>>>(cpart, b2, a2, 131072, 1024, 8);
    gemm256<false, 0, false, true><<<dim3(8, 16, 8), 256, 0, stream>>>(a2, w3, nullptr, cpart, 512, 1024, 1024, 128);
    reduce_bias_relu<<<512, 256, 0, stream>>>(cpart, b3, a1, 131072, 1024, 8);
    gemm256<false, 0, false, true><<<dim3(8, 16, 8), 256, 0, stream>>>(a1, w4, nullptr, cpart, 512, 1024, 1024, 128);
    reduce_bias_relu<<<512, 256, 0, stream>>>(cpart, b4, a2, 131072, 1024, 8);

    // ---- final layer + softmax ----
    final_kernel<<<8, 256, 0, stream>>>(a2, w5, b5, out);
}

// Round 4
// 369.255 us; speedup vs baseline: 7.0835x; 1.2317x over previous
//
#include <hip/hip_runtime.h>
#include <hip/hip_bf16.h>

__device__ __forceinline__ float eluf(float x) {
    return x > 0.f ? x : expm1f(x);
}

// C[M,N] = act( A'[M,K] @ B[N,K]^T + bias ), A' = ELU_A ? elu(A) : A
// ACT: 0 = none, 1 = relu.  SPLIT: write raw partial to C + blockIdx.z*M*N,
// covering K-chunk [blockIdx.z*kChunk, +kChunk)
template<bool ELU_A, int ACT, bool BIAS, bool SPLIT>
__global__ __launch_bounds__(256) void gemm256(
    const float* __restrict__ A, const float* __restrict__ B,
    const float* __restrict__ bias, float* __restrict__ C,
    int M, int N, int K, int kChunk)
{
    constexpr int BM = 64, BN = 64, BK = 16;
    __shared__ float As[BK][BM + 4];
    __shared__ float Bs[BK][BN + 4];
    const int t  = threadIdx.x;
    const int tx = t & 15;    // n-group (16 x 4 cols)
    const int ty = t >> 4;    // m-group (16 x 4 rows)
    const int m0 = blockIdx.x * BM;
    const int n0 = blockIdx.y * BN;
    const int kBeg = SPLIT ? blockIdx.z * kChunk : 0;
    const int kEnd = SPLIT ? kBeg + kChunk : K;

    const int sr = t >> 2;    // staging row 0..63
    const int sc = t & 3;     // staging col4 0..3

    float acc[4][4] = {};

    for (int k0 = kBeg; k0 < kEnd; k0 += BK) {
        {
            int row = m0 + sr;
            float4 v = make_float4(0.f, 0.f, 0.f, 0.f);
            if (row < M) v = *(const float4*)&A[(size_t)row * K + k0 + sc * 4];
            if (ELU_A) { v.x = eluf(v.x); v.y = eluf(v.y); v.z = eluf(v.z); v.w = eluf(v.w); }
            As[sc * 4 + 0][sr] = v.x; As[sc * 4 + 1][sr] = v.y;
            As[sc * 4 + 2][sr] = v.z; As[sc * 4 + 3][sr] = v.w;
        }
        {
            float4 v = *(const float4*)&B[(size_t)(n0 + sr) * K + k0 + sc * 4];
            Bs[sc * 4 + 0][sr] = v.x; Bs[sc * 4 + 1][sr] = v.y;
            Bs[sc * 4 + 2][sr] = v.z; Bs[sc * 4 + 3][sr] = v.w;
        }
        __syncthreads();
        #pragma unroll
        for (int k = 0; k < BK; ++k) {
            float a[4], b[4];
            *(float4*)&a[0] = *(const float4*)&As[k][ty * 4];
            *(float4*)&b[0] = *(const float4*)&Bs[k][tx * 4];
            #pragma unroll
            for (int i = 0; i < 4; ++i)
                #pragma unroll
                for (int j = 0; j < 4; ++j)
                    acc[i][j] = fmaf(a[i], b[j], acc[i][j]);
        }
        __syncthreads();
    }

    float* Cw = SPLIT ? C + (size_t)blockIdx.z * M * N : C;
    #pragma unroll
    for (int i = 0; i < 4; ++i) {
        int row = m0 + ty * 4 + i;
        if (row >= M) continue;
        float4 v;
        float* vp = (float*)&v;
        #pragma unroll
        for (int j = 0; j < 4; ++j) {
            float xv = acc[i][j];
            if (!SPLIT) {
                if (BIAS) xv += bias[n0 + tx * 4 + j];
                if (ACT == 1) xv = fmaxf(xv, 0.f);
            }
            vp[j] = xv;
        }
        *(float4*)&Cw[(size_t)row * N + n0 + tx * 4] = v;
    }
}

// C[i] = relu( sum_z part[z][i] + bias[i % N] ), float4-wide
__global__ __launch_bounds__(256) void reduce_bias_relu(
    const float* __restrict__ part, const float* __restrict__ bias,
    float* __restrict__ C, int MN4, int N, int KS)
{
    int i = blockIdx.x * 256 + threadIdx.x;
    if (i >= MN4) return;
    float4 s = *(const float4*)&part[(size_t)i * 4];
    for (int z = 1; z < KS; ++z) {
        float4 p = *(const float4*)&part[(size_t)z * MN4 * 4 + (size_t)i * 4];
        s.x += p.x; s.y += p.y; s.z += p.z; s.w += p.w;
    }
    float4 bv = *(const float4*)&bias[(i * 4) & (N - 1)];
    s.x = fmaxf(s.x + bv.x, 0.f);
    s.y = fmaxf(s.y + bv.y, 0.f);
    s.z = fmaxf(s.z + bv.z, 0.f);
    s.w = fmaxf(s.w + bv.w, 0.f);
    *(float4*)&C[(size_t)i * 4] = s;
}

// ---------- CSR build ----------
__global__ __launch_bounds__(256) void hist_kernel(
    const int* __restrict__ row, int* __restrict__ deg, int E)
{
    for (int e = blockIdx.x * 256 + threadIdx.x; e < E; e += gridDim.x * 256)
        atomicAdd(&deg[row[e]], 1);
}

__global__ __launch_bounds__(256) void scan1_kernel(
    const int* __restrict__ deg, int* __restrict__ part,
    int* __restrict__ blocksum, int n)
{
    __shared__ int s[256];
    int i = blockIdx.x * 256 + threadIdx.x;
    int v = (i < n) ? deg[i] : 0;
    s[threadIdx.x] = v;
    __syncthreads();
    #pragma unroll
    for (int off = 1; off < 256; off <<= 1) {
        int t = (threadIdx.x >= off) ? s[threadIdx.x - off] : 0;
        __syncthreads();
        if (threadIdx.x >= off) s[threadIdx.x] += t;
        __syncthreads();
    }
    if (i < n) part[i] = s[threadIdx.x] - v;   // exclusive
    if (threadIdx.x == 255) blocksum[blockIdx.x] = s[255];
}

__global__ __launch_bounds__(256) void scan2_kernel(
    const int* __restrict__ blocksum, int* __restrict__ blockoff, int nb)
{
    __shared__ int s[256];
    int v = (threadIdx.x < nb) ? blocksum[threadIdx.x] : 0;
    s[threadIdx.x] = v;
    __syncthreads();
    #pragma unroll
    for (int off = 1; off < 256; off <<= 1) {
        int t = (threadIdx.x >= off) ? s[threadIdx.x - off] : 0;
        __syncthreads();
        if (threadIdx.x >= off) s[threadIdx.x] += t;
        __syncthreads();
    }
    blockoff[threadIdx.x] = s[threadIdx.x] - v;   // exclusive
}

__global__ __launch_bounds__(256) void scan3_kernel(
    const int* __restrict__ part, const int* __restrict__ blockoff,
    int* __restrict__ rowptr, int* __restrict__ cursor, int n, int E)
{
    int i = blockIdx.x * 256 + threadIdx.x;
    if (i < n) {
        int v = part[i] + blockoff[i >> 8];
        rowptr[i] = v;
        cursor[i] = v;
    }
    if (i == 0) rowptr[n] = E;
}

__global__ __launch_bounds__(256) void scatter_cols_kernel(
    const int* __restrict__ row, const int* __restrict__ col,
    int* __restrict__ cursor, int* __restrict__ ecol, int E)
{
    for (int e = blockIdx.x * 256 + threadIdx.x; e < E; e += gridDim.x * 256) {
        int p = atomicAdd(&cursor[row[e]], 1);
        ecol[p] = col[e];
    }
}

// ---------- gather-sum:  h[n] = sum_{e in csr row n} z[ecol[e]]  ----------
template<int DQ>
__global__ __launch_bounds__(256) void gather_sum(
    const int* __restrict__ rowptr, const int* __restrict__ ecol,
    const float* __restrict__ z, float* __restrict__ h, int N)
{
    constexpr int GPB = 256 / DQ;
    const int node = blockIdx.x * GPB + threadIdx.x / DQ;
    const int lane = threadIdx.x % DQ;
    if (node >= N) return;
    const int start = rowptr[node], end = rowptr[node + 1];
    float ax = 0.f, ay = 0.f, az = 0.f, aw = 0.f;
    for (int base = start; base < end; base += DQ) {
        int myidx = base + lane;
        int c = (myidx < end) ? ecol[myidx] : 0;
        int cnt = min(DQ, end - base);
        for (int j = 0; j < cnt; ++j) {
            int cj = __shfl(c, j, DQ);
            float4 zv = *(const float4*)&z[(size_t)cj * (DQ * 4) + lane * 4];
            ax += zv.x; ay += zv.y; az += zv.z; aw += zv.w;
        }
    }
    *(float4*)&h[(size_t)node * (DQ * 4) + lane * 4] = make_float4(ax, ay, az, aw);
}

// ---------- sorted-batch mean pool ----------
// bstart[b] = first node index with batch[node] >= b   (batch is sorted)
__global__ __launch_bounds__(256) void bounds_kernel(
    const int* __restrict__ batch, int* __restrict__ bstart, int N, int B)
{
    int b = blockIdx.x * 256 + threadIdx.x;
    if (b > B) return;
    int lo = 0, hi = N;
    while (lo < hi) {
        int mid = (lo + hi) >> 1;
        if (batch[mid] < b) lo = mid + 1; else hi = mid;
    }
    bstart[b] = lo;
}

// one block per graph: mean over contiguous node range, 64 dims
__global__ __launch_bounds__(256) void pool_sorted(
    const float* __restrict__ h2, const int* __restrict__ bstart,
    float* __restrict__ g)
{
    __shared__ float4 s[256];
    const int b  = blockIdx.x;
    const int c4 = threadIdx.x & 15;   // float4 column
    const int rg = threadIdx.x >> 4;   // row group 0..15
    const int start = bstart[b], end = bstart[b + 1];
    float4 acc = make_float4(0.f, 0.f, 0.f, 0.f);
    for (int r = start + rg; r < end; r += 16) {
        float4 v = *(const float4*)&h2[(size_t)r * 64 + c4 * 4];
        acc.x += v.x; acc.y += v.y; acc.z += v.z; acc.w += v.w;
    }
    s[threadIdx.x] = acc;
    __syncthreads();
    #pragma unroll
    for (int off = 8; off >= 1; off >>= 1) {
        if (rg < off) {
            float4 o = s[(rg + off) * 16 + c4];
            float4 m = s[rg * 16 + c4];
            m.x += o.x; m.y += o.y; m.z += o.z; m.w += o.w;
            s[rg * 16 + c4] = m;
        }
        __syncthreads();
    }
    if (rg == 0) {
        float inv = 1.0f / fmaxf((float)(end - start), 1.0f);
        float4 m = s[c4];
        m.x *= inv; m.y *= inv; m.z *= inv; m.w *= inv;
        *(float4*)&g[(size_t)b * 64 + c4 * 4] = m;
    }
}

// out[512,4] = softmax( A[512,1024] @ W[4,1024]^T + bias )
__global__ __launch_bounds__(256) void final_kernel(
    const float* __restrict__ A, const float* __restrict__ W,
    const float* __restrict__ bias, float* __restrict__ out)
{
    int i = blockIdx.x * 256 + threadIdx.x;   // exactly 512*4
    int r = i >> 2, o = i & 3;
    float s = bias[o];
    const float4* a = (const float4*)&A[(size_t)r * 1024];
    const float4* w = (const float4*)&W[(size_t)o * 1024];
    #pragma unroll 4
    for (int k = 0; k < 256; ++k) {
        float4 av = a[k], wv = w[k];
        s += av.x * wv.x + av.y * wv.y + av.z * wv.z + av.w * wv.w;
    }
    float m = s;
    m = fmaxf(m, __shfl_xor(m, 1));
    m = fmaxf(m, __shfl_xor(m, 2));
    float e = __expf(s - m);
    float sum = e;
    sum += __shfl_xor(sum, 1);
    sum += __shfl_xor(sum, 2);
    out[i] = e / sum;
}

extern "C" void kernel_launch(void* const* d_in, const int* in_sizes, int n_in,
                              void* d_out, int out_size, void* d_ws, size_t ws_size,
                              hipStream_t stream)
{
    const float* x     = (const float*)d_in[0];
    const int*   ei    = (const int*)d_in[1];
    const int*   batch = (const int*)d_in[2];
    const float* fc1_w = (const float*)d_in[3];   // [4,32,128] -> [128,128]
    const float* fc2_w = (const float*)d_in[5];   // [1,64,128] -> [64,128]
    const float* w1 = (const float*)d_in[7];  const float* b1 = (const float*)d_in[8];
    const float* w2 = (const float*)d_in[9];  const float* b2 = (const float*)d_in[10];
    const float* w3 = (const float*)d_in[11]; const float* b3 = (const float*)d_in[12];
    const float* w4 = (const float*)d_in[13]; const float* b4 = (const float*)d_in[14];
    const float* w5 = (const float*)d_in[15]; const float* b5 = (const float*)d_in[16];
    float* out = (float*)d_out;

    const int N = 50000, E = 800000, B = 512;
    const int* rowp = ei;        // edge_index[0]  (destinations)
    const int* colp = ei + E;    // edge_index[1]  (sources)

    // ---- workspace layout (floats) ----
    float* ws   = (float*)d_ws;
    float* bufA = ws;                         // 6,400,000  (z1, then z2)
    float* bufB = ws + 6400000;               // 6,400,000  (h1, then h2, then split-K partials)
    float* g    = ws + 12800000;              // 32768
    int* rowptr = (int*)(g + 32768);          // 50001 (pad to 50004)
    int* ecol   = rowptr + 50004;             // 800000
    int* bstart = ecol + 800000;              // 513 (pad 516)
    // MLP activations alias bufA (free after gather2 reads z2)
    float* a1 = bufA;                         // 524288
    float* a2 = bufA + 524288;                // 524288
    float* cpart = bufB;                      // 8 * 524288 (bufB free after pool)
    // CSR-build temporaries alias bufA/bufB (free before GEMM1)
    int* deg      = (int*)bufA;               // 50000
    int* part     = (int*)bufA + 65536;       // 50000
    int* blocksum = (int*)bufA + 131072;      // 256
    int* blockoff = (int*)bufA + 131328;      // 256
    int* cursor   = (int*)bufB;               // 50000

    const int NB = (N + 255) / 256;           // 196 scan blocks

    // ---- build CSR (group edges by destination row) ----
    hipMemsetAsync(deg, 0, (size_t)N * sizeof(int), stream);
    hist_kernel<<<1024, 256, 0, stream>>>(rowp, deg, E);
    scan1_kernel<<<NB, 256, 0, stream>>>(deg, part, blocksum, N);
    scan2_kernel<<<1, 256, 0, stream>>>(blocksum, blockoff, NB);
    scan3_kernel<<<NB, 256, 0, stream>>>(part, blockoff, rowptr, cursor, N, E);
    scatter_cols_kernel<<<1024, 256, 0, stream>>>(rowp, colp, cursor, ecol, E);
    bounds_kernel<<<3, 256, 0, stream>>>(batch, bstart, N, B);

    // ---- layer 1: z1 = x @ W1^T ; h1 = gather-sum(z1) ----
    gemm256<false, 0, false, false><<<dim3(782, 2, 1), 256, 0, stream>>>(x, fc1_w, nullptr, bufA, N, 128, 128, 0);
    gather_sum<32><<<(N + 7) / 8, 256, 0, stream>>>(rowptr, ecol, bufA, bufB, N);

    // ---- layer 2: z2 = elu(h1) @ W2^T ; h2 = gather-sum(z2) ----
    gemm256<true, 0, false, false><<<dim3(782, 1, 1), 256, 0, stream>>>(bufB, fc2_w, nullptr, bufA, N, 64, 128, 0);
    gather_sum<16><<<(N + 15) / 16, 256, 0, stream>>>(rowptr, ecol, bufA, bufB, N);

    // ---- mean-pool by graph (batch sorted -> contiguous ranges) ----
    pool_sorted<<<B, 256, 0, stream>>>(bufB, bstart, g);

    // ---- MLP ----
    gemm256<false, 1, true, false><<<dim3(8, 16, 1), 256, 0, stream>>>(g, w1, b1, a1, 512, 1024, 64, 0);
    gemm256<false, 0, false, true><<<dim3(8, 16, 8), 256, 0, stream>>>(a1, w2, nullptr, cpart, 512, 1024, 1024, 128);
    reduce_bias_relu<<<512, 256, 0, stream>>>(cpart, b2, a2, 131072, 1024, 8);
    gemm256<false, 0, false, true><<<dim3(8, 16, 8), 256, 0, stream>>>(a2, w3, nullptr, cpart, 512, 1024, 1024, 128);
    reduce_bias_relu<<<512, 256, 0, stream>>>(cpart, b3, a1, 131072, 1024, 8);
    gemm256<false, 0, false, true><<<dim3(8, 16, 8), 256, 0, stream>>>(a1, w4, nullptr, cpart, 512, 1024, 1024, 128);
    reduce_bias_relu<<<512, 256, 0, stream>>>(cpart, b4, a2, 131072, 1024, 8);

    // ---- final layer + softmax ----
    final_kernel<<<8, 256, 0, stream>>>(a2, w5, b5, out);
}

// Round 5
// 348.050 us; speedup vs baseline: 7.5150x; 1.0609x over previous
//
#include <hip/hip_runtime.h>
#include <hip/hip_bf16.h>

__device__ __forceinline__ float eluf(float x) {
    return x > 0.f ? x : expm1f(x);
}

// C[M,N] = act( A'[M,K] @ B[N,K]^T + bias ), A' = ELU_A ? elu(A) : A
// ACT: 0 = none, 1 = relu.  SPLIT: write raw partial to C + blockIdx.z*M*N
template<bool ELU_A, int ACT, bool BIAS, bool SPLIT>
__global__ __launch_bounds__(256) void gemm256(
    const float* __restrict__ A, const float* __restrict__ B,
    const float* __restrict__ bias, float* __restrict__ C,
    int M, int N, int K, int kChunk)
{
    constexpr int BM = 64, BN = 64, BK = 16;
    __shared__ float As[BK][BM + 4];
    __shared__ float Bs[BK][BN + 4];
    const int t  = threadIdx.x;
    const int tx = t & 15;
    const int ty = t >> 4;
    const int m0 = blockIdx.x * BM;
    const int n0 = blockIdx.y * BN;
    const int kBeg = SPLIT ? blockIdx.z * kChunk : 0;
    const int kEnd = SPLIT ? kBeg + kChunk : K;

    const int sr = t >> 2;
    const int sc = t & 3;

    float acc[4][4] = {};

    for (int k0 = kBeg; k0 < kEnd; k0 += BK) {
        {
            int row = m0 + sr;
            float4 v = make_float4(0.f, 0.f, 0.f, 0.f);
            if (row < M) v = *(const float4*)&A[(size_t)row * K + k0 + sc * 4];
            if (ELU_A) { v.x = eluf(v.x); v.y = eluf(v.y); v.z = eluf(v.z); v.w = eluf(v.w); }
            As[sc * 4 + 0][sr] = v.x; As[sc * 4 + 1][sr] = v.y;
            As[sc * 4 + 2][sr] = v.z; As[sc * 4 + 3][sr] = v.w;
        }
        {
            float4 v = *(const float4*)&B[(size_t)(n0 + sr) * K + k0 + sc * 4];
            Bs[sc * 4 + 0][sr] = v.x; Bs[sc * 4 + 1][sr] = v.y;
            Bs[sc * 4 + 2][sr] = v.z; Bs[sc * 4 + 3][sr] = v.w;
        }
        __syncthreads();
        #pragma unroll
        for (int k = 0; k < BK; ++k) {
            float a[4], b[4];
            *(float4*)&a[0] = *(const float4*)&As[k][ty * 4];
            *(float4*)&b[0] = *(const float4*)&Bs[k][tx * 4];
            #pragma unroll
            for (int i = 0; i < 4; ++i)
                #pragma unroll
                for (int j = 0; j < 4; ++j)
                    acc[i][j] = fmaf(a[i], b[j], acc[i][j]);
        }
        __syncthreads();
    }

    float* Cw = SPLIT ? C + (size_t)blockIdx.z * M * N : C;
    #pragma unroll
    for (int i = 0; i < 4; ++i) {
        int row = m0 + ty * 4 + i;
        if (row >= M) continue;
        float4 v;
        float* vp = (float*)&v;
        #pragma unroll
        for (int j = 0; j < 4; ++j) {
            float xv = acc[i][j];
            if (!SPLIT) {
                if (BIAS) xv += bias[n0 + tx * 4 + j];
                if (ACT == 1) xv = fmaxf(xv, 0.f);
            }
            vp[j] = xv;
        }
        *(float4*)&Cw[(size_t)row * N + n0 + tx * 4] = v;
    }
}

// In-place: A[m0:m0+64, 0:128] = A_tile @ W^T, K = N = 128.
// Block stages its OWN 64 rows + full W into LDS, then overwrites its rows.
__global__ __launch_bounds__(256) void gemm_inplace_128(
    float* __restrict__ A, const float* __restrict__ W, int M)
{
    __shared__ float As[128][68];    // [k][row]
    __shared__ float Ws[128][132];   // [k][n]
    const int t  = threadIdx.x;
    const int m0 = blockIdx.x * 64;

    for (int idx = t; idx < 2048; idx += 256) {       // 64 rows x 32 float4
        int row = idx >> 5, c4 = idx & 31;
        int grow = m0 + row;
        float4 v = make_float4(0.f, 0.f, 0.f, 0.f);
        if (grow < M) v = *(const float4*)&A[(size_t)grow * 128 + c4 * 4];
        As[c4 * 4 + 0][row] = v.x; As[c4 * 4 + 1][row] = v.y;
        As[c4 * 4 + 2][row] = v.z; As[c4 * 4 + 3][row] = v.w;
    }
    for (int idx = t; idx < 4096; idx += 256) {       // 128 rows x 32 float4
        int n = idx >> 5, c4 = idx & 31;
        float4 v = *(const float4*)&W[(size_t)n * 128 + c4 * 4];
        Ws[c4 * 4 + 0][n] = v.x; Ws[c4 * 4 + 1][n] = v.y;
        Ws[c4 * 4 + 2][n] = v.z; Ws[c4 * 4 + 3][n] = v.w;
    }
    __syncthreads();

    const int tx = t & 15, ty = t >> 4;   // ty: 4 rows each, tx: 8 cols each
    float acc[4][8] = {};
    for (int k = 0; k < 128; ++k) {
        float a[4], w[8];
        #pragma unroll
        for (int i = 0; i < 4; ++i) a[i] = As[k][ty * 4 + i];
        *(float4*)&w[0] = *(const float4*)&Ws[k][tx * 8];
        *(float4*)&w[4] = *(const float4*)&Ws[k][tx * 8 + 4];
        #pragma unroll
        for (int i = 0; i < 4; ++i)
            #pragma unroll
            for (int j = 0; j < 8; ++j)
                acc[i][j] = fmaf(a[i], w[j], acc[i][j]);
    }

    #pragma unroll
    for (int i = 0; i < 4; ++i) {
        int grow = m0 + ty * 4 + i;
        if (grow >= M) continue;
        float4 v0, v1;
        v0.x = acc[i][0]; v0.y = acc[i][1]; v0.z = acc[i][2]; v0.w = acc[i][3];
        v1.x = acc[i][4]; v1.y = acc[i][5]; v1.z = acc[i][6]; v1.w = acc[i][7];
        *(float4*)&A[(size_t)grow * 128 + tx * 8]     = v0;
        *(float4*)&A[(size_t)grow * 128 + tx * 8 + 4] = v1;
    }
}

// C[i] = relu( sum_z part[z][i] + bias[i % N] ), float4-wide
__global__ __launch_bounds__(256) void reduce_bias_relu(
    const float* __restrict__ part, const float* __restrict__ bias,
    float* __restrict__ C, int MN4, int N, int KS)
{
    int i = blockIdx.x * 256 + threadIdx.x;
    if (i >= MN4) return;
    float4 s = *(const float4*)&part[(size_t)i * 4];
    for (int z = 1; z < KS; ++z) {
        float4 p = *(const float4*)&part[(size_t)z * MN4 * 4 + (size_t)i * 4];
        s.x += p.x; s.y += p.y; s.z += p.z; s.w += p.w;
    }
    float4 bv = *(const float4*)&bias[(i * 4) & (N - 1)];
    s.x = fmaxf(s.x + bv.x, 0.f);
    s.y = fmaxf(s.y + bv.y, 0.f);
    s.z = fmaxf(s.z + bv.z, 0.f);
    s.w = fmaxf(s.w + bv.w, 0.f);
    *(float4*)&C[(size_t)i * 4] = s;
}

// ---------- one-pass ELL build: ell[r*64 + p] = col, p = cnt[r]++ ----------
__global__ __launch_bounds__(256) void scatter_ell(
    const int* __restrict__ row, const int* __restrict__ col,
    int* __restrict__ cnt, int* __restrict__ ell, int E)
{
    int e = blockIdx.x * 256 + threadIdx.x;
    if (e >= E) return;
    int r = row[e];
    int p = atomicAdd(&cnt[r], 1);
    if (p < 64) ell[(size_t)r * 64 + p] = col[e];
}

// ---------- gather-sum over ELL:  h[n] = sum_j z[ell[n][j]] ----------
template<int DQ>   // DQ lanes per node, D = DQ*4
__global__ __launch_bounds__(256) void gather_sum_ell(
    const int* __restrict__ ell, const int* __restrict__ cnt,
    const float* __restrict__ z, float* __restrict__ h, int N)
{
    constexpr int GPB = 256 / DQ;
    const int node = blockIdx.x * GPB + threadIdx.x / DQ;
    const int lane = threadIdx.x % DQ;
    if (node >= N) return;
    const int deg = cnt[node];
    const size_t base = (size_t)node * 64;
    float ax = 0.f, ay = 0.f, az = 0.f, aw = 0.f;
    for (int b0 = 0; b0 < deg; b0 += DQ) {
        int c = (b0 + lane < deg) ? ell[base + b0 + lane] : 0;
        int m = min(DQ, deg - b0);
        for (int j = 0; j < m; ++j) {
            int cj = __shfl(c, j, DQ);
            float4 zv = *(const float4*)&z[(size_t)cj * (DQ * 4) + lane * 4];
            ax += zv.x; ay += zv.y; az += zv.z; aw += zv.w;
        }
    }
    *(float4*)&h[(size_t)node * (DQ * 4) + lane * 4] = make_float4(ax, ay, az, aw);
}

// ---------- sorted-batch mean pool ----------
__global__ __launch_bounds__(256) void bounds_kernel(
    const int* __restrict__ batch, int* __restrict__ bstart, int N, int B)
{
    int b = blockIdx.x * 256 + threadIdx.x;
    if (b > B) return;
    int lo = 0, hi = N;
    while (lo < hi) {
        int mid = (lo + hi) >> 1;
        if (batch[mid] < b) lo = mid + 1; else hi = mid;
    }
    bstart[b] = lo;
}

__global__ __launch_bounds__(256) void pool_sorted(
    const float* __restrict__ h2, const int* __restrict__ bstart,
    float* __restrict__ g)
{
    __shared__ float4 s[256];
    const int b  = blockIdx.x;
    const int c4 = threadIdx.x & 15;
    const int rg = threadIdx.x >> 4;
    const int start = bstart[b], end = bstart[b + 1];
    float4 acc = make_float4(0.f, 0.f, 0.f, 0.f);
    for (int r = start + rg; r < end; r += 16) {
        float4 v = *(const float4*)&h2[(size_t)r * 64 + c4 * 4];
        acc.x += v.x; acc.y += v.y; acc.z += v.z; acc.w += v.w;
    }
    s[threadIdx.x] = acc;
    __syncthreads();
    #pragma unroll
    for (int off = 8; off >= 1; off >>= 1) {
        if (rg < off) {
            float4 o = s[(rg + off) * 16 + c4];
            float4 m = s[rg * 16 + c4];
            m.x += o.x; m.y += o.y; m.z += o.z; m.w += o.w;
            s[rg * 16 + c4] = m;
        }
        __syncthreads();
    }
    if (rg == 0) {
        float inv = 1.0f / fmaxf((float)(end - start), 1.0f);
        float4 m = s[c4];
        m.x *= inv; m.y *= inv; m.z *= inv; m.w *= inv;
        *(float4*)&g[(size_t)b * 64 + c4 * 4] = m;
    }
}

// out[512,4] = softmax( A[512,1024] @ W[4,1024]^T + bias )
__global__ __launch_bounds__(256) void final_kernel(
    const float* __restrict__ A, const float* __restrict__ W,
    const float* __restrict__ bias, float* __restrict__ out)
{
    int i = blockIdx.x * 256 + threadIdx.x;
    int r = i >> 2, o = i & 3;
    float s = bias[o];
    const float4* a = (const float4*)&A[(size_t)r * 1024];
    const float4* w = (const float4*)&W[(size_t)o * 1024];
    #pragma unroll 4
    for (int k = 0; k < 256; ++k) {
        float4 av = a[k], wv = w[k];
        s += av.x * wv.x + av.y * wv.y + av.z * wv.z + av.w * wv.w;
    }
    float m = s;
    m = fmaxf(m, __shfl_xor(m, 1));
    m = fmaxf(m, __shfl_xor(m, 2));
    float e = __expf(s - m);
    float sum = e;
    sum += __shfl_xor(sum, 1);
    sum += __shfl_xor(sum, 2);
    out[i] = e / sum;
}

extern "C" void kernel_launch(void* const* d_in, const int* in_sizes, int n_in,
                              void* d_out, int out_size, void* d_ws, size_t ws_size,
                              hipStream_t stream)
{
    const float* x     = (const float*)d_in[0];
    const int*   ei    = (const int*)d_in[1];
    const int*   batch = (const int*)d_in[2];
    const float* fc1_w = (const float*)d_in[3];   // [4,32,128] -> [128,128]
    const float* fc2_w = (const float*)d_in[5];   // [1,64,128] -> [64,128]
    const float* w1 = (const float*)d_in[7];  const float* b1 = (const float*)d_in[8];
    const float* w2 = (const float*)d_in[9];  const float* b2 = (const float*)d_in[10];
    const float* w3 = (const float*)d_in[11]; const float* b3 = (const float*)d_in[12];
    const float* w4 = (const float*)d_in[13]; const float* b4 = (const float*)d_in[14];
    const float* w5 = (const float*)d_in[15]; const float* b5 = (const float*)d_in[16];
    float* out = (float*)d_out;

    const int N = 50000, E = 800000, B = 512;
    const int* rowp = ei;        // destinations
    const int* colp = ei + E;    // sources

    // ---- workspace layout ----
    // bufA [6.4M f]: gx/h1 (25.6MB) -> h2 (first 3.2M f) + a1/a2 (after 3.2M f)
    // bufB [6.4M f]: ELL (first 3.2M ints) + z2 (floats 3.2M..6.4M) -> cpart (MLP)
    float* ws   = (float*)d_ws;
    float* bufA = ws;
    float* bufB = ws + 6400000;
    float* g    = ws + 12800000;              // 32768 f
    int* cnt    = (int*)(g + 32768);          // 50000
    int* bstart = cnt + 50000;                // 513 (pad 516)

    int*   ell  = (int*)bufB;                 // 50000*64 = 3.2M ints
    float* z2   = bufB + 3200000;             // 50000*64 floats
    float* h2   = bufA;                       // 50000*64 floats
    float* a1   = bufA + 3200000;             // 524288
    float* a2   = a1 + 524288;                // 524288
    float* cpart = bufB;                      // 8*524288 (after ELL/z2 dead)

    // ---- build ELL adjacency (one pass) + graph bounds ----
    hipMemsetAsync(cnt, 0, (size_t)N * sizeof(int), stream);
    scatter_ell<<<(E + 255) / 256, 256, 0, stream>>>(rowp, colp, cnt, ell, E);
    bounds_kernel<<<3, 256, 0, stream>>>(batch, bstart, N, B);

    // ---- layer 1:  h1 = (gather-sum x) @ W1^T  (linearity of the sum) ----
    gather_sum_ell<32><<<(N + 7) / 8, 256, 0, stream>>>(ell, cnt, x, bufA, N);
    gemm_inplace_128<<<782, 256, 0, stream>>>(bufA, fc1_w, N);

    // ---- layer 2:  z2 = elu(h1) @ W2^T ; h2 = gather-sum(z2) ----
    gemm256<true, 0, false, false><<<dim3(782, 1, 1), 256, 0, stream>>>(bufA, fc2_w, nullptr, z2, N, 64, 128, 0);
    gather_sum_ell<16><<<(N + 15) / 16, 256, 0, stream>>>(ell, cnt, z2, h2, N);

    // ---- mean-pool by graph ----
    pool_sorted<<<B, 256, 0, stream>>>(h2, bstart, g);

    // ---- MLP ----
    gemm256<false, 1, true, false><<<dim3(8, 16, 1), 256, 0, stream>>>(g, w1, b1, a1, 512, 1024, 64, 0);
    gemm256<false, 0, false, true><<<dim3(8, 16, 8), 256, 0, stream>>>(a1, w2, nullptr, cpart, 512, 1024, 1024, 128);
    reduce_bias_relu<<<512, 256, 0, stream>>>(cpart, b2, a2, 131072, 1024, 8);
    gemm256<false, 0, false, true><<<dim3(8, 16, 8), 256, 0, stream>>>(a2, w3, nullptr, cpart, 512, 1024, 1024, 128);
    reduce_bias_relu<<<512, 256, 0, stream>>>(cpart, b3, a1, 131072, 1024, 8);
    gemm256<false, 0, false, true><<<dim3(8, 16, 8), 256, 0, stream>>>(a1, w4, nullptr, cpart, 512, 1024, 1024, 128);
    reduce_bias_relu<<<512, 256, 0, stream>>>(cpart, b4, a2, 131072, 1024, 8);

    // ---- final layer + softmax ----
    final_kernel<<<8, 256, 0, stream>>>(a2, w5, b5, out);
}